// Round 8
// baseline (694.731 us; speedup 1.0000x reference)
//
#include <hip/hip_runtime.h>
#include <cmath>

// ============================================================================
// ConvMod1D fused kernel — round 8: r7 convmod (397us, verified) + fast aux.
// convmod delta: s_setprio(1) around MFMA k-loop only (T5; 2 co-resident
// blocks/CU at different phases = the wave-role diversity setprio needs).
// ln1pre: 4-way c-split (256thr = 64 l x 4 cgroups, LDS reduce) — cuts the
// 256-deep stride-16KB serial load chain 4x. grid 2048.
// uv: wave-per-output (640 blocks x 64 lanes, shfl_down reduce) vs 640
// threads with serial 128-192 loops on 5 CUs.
// TL=64 (halo 12 -> EXT=88), 512 thr, 6 LDS slots RS=72 -> 76.0 KB =>
// 2 blocks/CU. Wave grid 4Mx2N, NT=3 BLOCKED. LN folding (r7):
//   pw(LN(x)) = rs_e*(W'@x_raw) + (u_o - muRS_e*v_o);  W' = W*diag(ln_w).
//
// Slot schedule (S0..S5; stale data only feeds masked cols / finite bf16):
//  pre: meanA/rstdA <- stats | P0 xs0n->S0, xs1n->S1 [0,88)
//  P1 g1pv1: S0 -> g1:S2, pv1:S3 [0,88); pwv12: S1->S4 [2,86)
//  P2 a1=dw7(S2)->S5 + t1=a1*pv1 in-place S3   [3,85)
//  P3 mul1=pw(S3)->S2, x1low=dw3(S4)+S5->S1    [3,85)
//  P4 ln2 STATS over raw {S1,S2} [3,85) -> rsB, muRSB
//  P5 xs2n->S0 [6,82); g2(LNF):{S1,S2}->{S3,S4} [3,85);
//     pv2(LNF,INPL):{S1,S2}->{S1,S2} [7,81)
//  P6 pwv22: S0->S5 [6,82), a2=dw9 INPL {S3,S4} + t2 in-place {S1,S2} [7,81)
//  P7 p2a: {S3,S4}->S0 [7,81), mul2 INPL {S1,S2} [7,81)
//  P8 x2low=dw3(S5)+S0->S3 [7,81)
//  P9 ln3 STATS over raw {S3,S1,S2} [7,81)
//  P10 g3(LNF):{S3,S1,S2}->{S4,S5,S0} [7,81);
//      pv3(LNF,INPL):{S3,S1,S2}->{S3,S1,S2} [12,76)
//  P11 a3=dw11 INPL {S4,S5,S0} + t3 in-place {S3,S1,S2} [12,76)
//  P12 mul3: pw(t3)->OUT[64:256] [12,76), p3a INPL {S4,S5,S0}->S4, xs3n->S5
//  P13 pwv32: S5->S0 [11,77)
//  P14 x3=dw3(S0)+S4->OUT[0:64] [12,76)
// ============================================================================

using u16 = unsigned short;
typedef short shrt8 __attribute__((ext_vector_type(8)));
typedef short shrt4 __attribute__((ext_vector_type(4)));
typedef float f32x4 __attribute__((ext_vector_type(4)));

#define DEVI __device__ __forceinline__

static constexpr int TL   = 64;          // useful positions per block
static constexpr int EXT  = 88;          // 64 useful + 2*12 halo
static constexpr int RS   = 72;          // row stride in u16 (64 + 8 pad)
static constexpr int SLOT = EXT * RS;    // 6336 u16 = 12672 B
static constexpr int NW   = 8;
static constexpr int NTHR = 512;

DEVI u16 f2bf(float f) {                 // RNE fp32 -> bf16
    unsigned u = __float_as_uint(f);
    u += 0x7FFFu + ((u >> 16) & 1u);
    return (u16)(u >> 16);
}
DEVI float bf2f(u16 h) { return __uint_as_float(((unsigned)h) << 16); }

// exact-GELU via Abramowitz-Stegun 7.1.26 erf (|err| <= 1.5e-7, branch-free)
DEVI float gelu_f(float x) {
    const float y  = x * 0.70710678118654752f;
    const float ay = fabsf(y);
    const float t  = __builtin_amdgcn_rcpf(fmaf(0.3275911f, ay, 1.0f));
    float p = 1.061405429f;
    p = fmaf(p, t, -1.453152027f);
    p = fmaf(p, t,  1.421413741f);
    p = fmaf(p, t, -0.284496736f);
    p = fmaf(p, t,  0.254829592f);
    float er = 1.0f - p * t * __expf(-ay * ay);
    er = copysignf(er, y);
    return 0.5f * x * (1.0f + er);
}

struct SL { int a, b, c; };
DEVI int slotOf(SL s, int ch) { return ch < 64 ? s.a : (ch < 128 ? s.b : s.c); }

// ---------------- pointwise conv via MFMA ------------------------------------
// Wave grid 4M x 2N; NT=3 BLOCKED n-tiles/wave (nt = nw*3 + ni).
// ch<OSPLIT -> outA (optional GELU, biasA); ch>=OSPLIT -> outB (biasB).
// Wb is [O,C] row-major. INPL: out aliases in -> barrier between k-loop and
// store. LNF: val = rs_e*acc + (u_ch - muRS_e*v_ch), uv = [u[0..O)|v[0..O)].
template<int O, int C, int OSPLIT, bool GELU, bool TOG, bool INPL, bool LNF>
DEVI void pw_mfma(u16* sh, SL in, SL outA, SL outB, const u16* Wb,
                  const float* biasA, const float* biasB,
                  int elo, int ehi, int l0,
                  const float* uv = nullptr, const float* rsA = nullptr,
                  const float* mrsA = nullptr,
                  float* outg = nullptr, int bidx = 0, int ochan = 0) {
    constexpr int MR = O / 64;           // m-tiles per wave (4 m-waves)
    constexpr int KT = C / 32;
    constexpr int NT = 3;
    const int lane = threadIdx.x & 63;
    const int wv   = threadIdx.x >> 6;
    const int mw = wv >> 1, nw = wv & 1;
    const int col  = lane & 15;
    const int quad = lane >> 4;
    const int mrow = mw * (MR * 16) + col;
    const int kq   = quad * 8;
    const int crow = mw * (MR * 16) + quad * 4;

    f32x4 acc[MR][NT];
    #pragma unroll
    for (int mi = 0; mi < MR; ++mi) {
        f32x4 bv;
        if (LNF) { bv[0] = 0.f; bv[1] = 0.f; bv[2] = 0.f; bv[3] = 0.f; }
        else {
            const int ch = crow + mi * 16;
            const float* bp = (OSPLIT < O && ch >= OSPLIT) ? (biasB + (ch - OSPLIT))
                                                           : (biasA + ch);
            bv = *(const f32x4*)bp;
        }
        #pragma unroll
        for (int ni = 0; ni < NT; ++ni) acc[mi][ni] = bv;
    }
    bool act[NT]; int bpos[NT];
    #pragma unroll
    for (int ni = 0; ni < NT; ++ni) {
        const int nt = nw * NT + ni;
        act[ni] = (nt * 16 < ehi) && (nt * 16 + 16 > elo);
        int p = nt * 16 + col; if (p > EXT - 1) p = EXT - 1;  // masked cols only
        bpos[ni] = p;
    }
    __builtin_amdgcn_s_setprio(1);       // T5: favor MFMA wave vs other block
    #pragma unroll
    for (int kt = 0; kt < KT; ++kt) {
        shrt8 af[MR];
        #pragma unroll
        for (int mi = 0; mi < MR; ++mi)
            af[mi] = *(const shrt8*)(Wb + (size_t)(mrow + mi * 16) * C + kt * 32 + kq);
        const int k0 = kt * 32;
        const u16* bs = sh + slotOf(in, k0) * SLOT + ((k0 & 63) + kq);
        #pragma unroll
        for (int ni = 0; ni < NT; ++ni) {
            if (!act[ni]) continue;
            const shrt8 bf = *(const shrt8*)(bs + bpos[ni] * RS);
            #pragma unroll
            for (int mi = 0; mi < MR; ++mi)
                acc[mi][ni] = __builtin_amdgcn_mfma_f32_16x16x32_bf16(af[mi], bf, acc[mi][ni], 0, 0, 0);
        }
    }
    __builtin_amdgcn_s_setprio(0);
    if (INPL) __syncthreads();           // all reads done before any store
    float rsv[NT], mrsv[NT];
    if (LNF) {
        #pragma unroll
        for (int ni = 0; ni < NT; ++ni) {
            rsv[ni]  = rsA[bpos[ni]];    // clamped pos: garbage only feeds masked stores
            mrsv[ni] = mrsA[bpos[ni]];
        }
    }
    #pragma unroll
    for (int mi = 0; mi < MR; ++mi) {
        const int ch = crow + mi * 16;
        const bool isA = !(OSPLIT < O) || (ch < OSPLIT);
        f32x4 u4, v4;
        if (LNF) {
            u4 = *(const f32x4*)(uv + ch);
            v4 = *(const f32x4*)(uv + O + ch);
        }
        #pragma unroll
        for (int ni = 0; ni < NT; ++ni) {
            if (!act[ni]) continue;
            const int e = (nw * NT + ni) * 16 + col;
            if (e < elo || e >= ehi) continue;
            const int l = l0 + e;
            f32x4 v = acc[mi][ni];
            if (LNF) {
                #pragma unroll
                for (int i = 0; i < 4; ++i)
                    v[i] = fmaf(rsv[ni], v[i], fmaf(-mrsv[ni], v4[i], u4[i]));
            }
            if (GELU && isA) { v[0]=gelu_f(v[0]); v[1]=gelu_f(v[1]); v[2]=gelu_f(v[2]); v[3]=gelu_f(v[3]); }
            if (TOG) {
                float* og = outg + ((size_t)bidx * 256 + ochan + ch) * 4096 + l;
                og[0] = v[0]; og[4096] = v[1]; og[2*4096] = v[2]; og[3*4096] = v[3];
            } else {
                const int cl = isA ? ch : ch - OSPLIT;
                const SL  os = isA ? outA : outB;
                const bool gv = (unsigned)l < 4096u;
                shrt4 pk;
                pk[0] = gv ? (short)f2bf(v[0]) : (short)0;
                pk[1] = gv ? (short)f2bf(v[1]) : (short)0;
                pk[2] = gv ? (short)f2bf(v[2]) : (short)0;
                pk[3] = gv ? (short)f2bf(v[3]) : (short)0;
                *(shrt4*)(sh + slotOf(os, cl) * SLOT + e * RS + (cl & 63)) = pk;
            }
        }
    }
}

// ---------------- depthwise conv fused with t = a*v, optional in-place -------
// One window of WIN positions per wave (tasks = (C/64)*nwin must be <= NW).
template<int C, int K, int PAD, int WIN, bool INPL>
DEVI void dw_mul(u16* sh, SL g, SL ao, SL v, const float* W, const float* bias,
                 int elo, int ehi) {
    const int lane = threadIdx.x & 63;
    const int wv   = threadIdx.x >> 6;
    const int nwin  = (ehi - elo + WIN - 1) / WIN;
    const int tasks = (C / 64) * nwin;       // <= NW by construction
    const bool have = wv < tasks;
    float r[K + WIN - 1];
    float wk[K];
    float bo = 0.f;
    int c = 0, e0 = 0;
    if (have) {
        const int cb = wv / nwin, wi = wv - cb * nwin;
        c = cb * 64 + lane;
        #pragma unroll
        for (int k = 0; k < K; ++k) wk[k] = W[c * K + k];
        bo = bias[c];
        e0 = elo + wi * WIN;
        const u16* si = sh + slotOf(g, c) * SLOT + lane;
        #pragma unroll
        for (int m = 0; m < K + WIN - 1; ++m) {
            int e = e0 - PAD + m; if (e > EXT - 1) e = EXT - 1;  // feeds masked outputs only
            r[m] = bf2f(si[e * RS]);
        }
    }
    if (INPL) __syncthreads();               // all reads done before any write
    if (have) {
        u16* sa = sh + slotOf(ao, c) * SLOT + lane;
        u16* sv = sh + slotOf(v, c) * SLOT + lane;
        #pragma unroll
        for (int j = 0; j < WIN; ++j) {
            const int e = e0 + j;
            if (e >= ehi) break;
            float acc = bo;
            #pragma unroll
            for (int k = 0; k < K; ++k) acc = fmaf(wk[k], r[j + k], acc);
            sa[e * RS] = f2bf(acc);                               // a
            sv[e * RS] = f2bf(acc * bf2f(sv[e * RS]));            // t = a*v (v masked 0 OOB)
        }
    }
}

// ---------------- depthwise conv (VALU), chan-per-lane, WIN-pos windows ------
template<int C, int K, int PAD, int WIN, bool ADD>
DEVI void dw_ph(u16* sh, SL in, SL add, SL out, const float* W, const float* bias,
                int elo, int ehi, int l0) {
    const int lane = threadIdx.x & 63;
    const int wv   = threadIdx.x >> 6;
    const int nwin = (ehi - elo + WIN - 1) / WIN;
    const int tasks = (C / 64) * nwin;
    for (int t = wv; t < tasks; t += NW) {
        const int cb = t / nwin, wi = t - cb * nwin;
        const int c = cb * 64 + lane;
        float wk[K];
        #pragma unroll
        for (int k = 0; k < K; ++k) wk[k] = W[c * K + k];
        const float bo = bias[c];
        const int e0 = elo + wi * WIN;
        const u16* si = sh + slotOf(in, c) * SLOT + lane;
        const u16* sa = ADD ? (sh + slotOf(add, c) * SLOT + lane) : nullptr;
        u16* so = sh + slotOf(out, c) * SLOT + lane;
        float r[K + WIN - 1];
        #pragma unroll
        for (int m = 0; m < K + WIN - 1; ++m) {
            int e = e0 - PAD + m; if (e > EXT - 1) e = EXT - 1;  // feeds masked outputs only
            r[m] = bf2f(si[e * RS]);
        }
        #pragma unroll
        for (int j = 0; j < WIN; ++j) {
            const int e = e0 + j;
            if (e >= ehi) break;
            float acc = bo;
            #pragma unroll
            for (int k = 0; k < K; ++k) acc = fmaf(wk[k], r[j + k], acc);
            if (ADD) acc += bf2f(sa[e * RS]);
            const bool gv = (unsigned)(l0 + e) < 4096u;
            so[e * RS] = gv ? f2bf(acc) : (u16)0;
        }
    }
}

// ---------------- LayerNorm statistics only (values stay RAW in LDS) ---------
// Writes rs[e] = rstd_e and muRS[e] = mu_e * rstd_e for e in [elo,ehi).
template<int C>
DEVI void ln_stats(u16* sh, SL s, int elo, int ehi, float* scr,
                   float* muRS, float* rs) {
    constexpr int P = C / 64;
    const int tid = threadIdx.x;
    const int nP = ehi - elo;
    if (tid < nP * P) {
        const int e = elo + tid / P;
        const int part = tid - (tid / P) * P;
        const u16* row = sh + slotOf(s, part * 64) * SLOT + e * RS;
        float sm = 0.f, sq = 0.f;
        #pragma unroll
        for (int j = 0; j < 8; ++j) {
            shrt8 v = *(const shrt8*)(row + j * 8);
            #pragma unroll
            for (int i = 0; i < 8; ++i) { float f = bf2f((u16)v[i]); sm += f; sq += f * f; }
        }
        scr[tid * 2] = sm; scr[tid * 2 + 1] = sq;
    }
    __syncthreads();
    if (tid < nP) {
        float sm = 0.f, sq = 0.f;
        for (int p = 0; p < P; ++p) { sm += scr[(tid * P + p) * 2]; sq += scr[(tid * P + p) * 2 + 1]; }
        const float mu = sm * (1.0f / C);
        const float va = sq * (1.0f / C) - mu * mu;
        const float r = rsqrtf(va + 1e-6f);
        rs[elo + tid] = r; muRS[elo + tid] = mu * r;
    }
}

// ---------------- load 64-chan chunk of x, apply LN1, store bf16 -------------
DEVI void norm_load(u16* sh, int slot, const float* xg, int b, int cbase,
                    const float* lnw, const float* lnb,
                    const float* mean, const float* rstd,
                    int elo, int ehi, int l0) {
    const int lane = threadIdx.x & 63;
    const int wv   = threadIdx.x >> 6;
    #pragma unroll
    for (int j = 0; j < 8; ++j) {
        const int o = wv + NW * j;
        const float* p = xg + ((size_t)b * 256 + cbase + o) * 4096;
        const float wo = lnw[cbase + o], bo = lnb[cbase + o];
        u16* r = sh + slot * SLOT + o;
        #pragma unroll
        for (int part = 0; part < 2; ++part) {
            const int e = elo + lane + part * 64;
            if (e < ehi) {
                const int l = l0 + e;
                const bool gv = (unsigned)l < 4096u;
                float v = gv ? p[l] : 0.f;
                v = (v - mean[e]) * rstd[e] * wo + bo;
                r[e * RS] = gv ? f2bf(v) : (u16)0;
            }
        }
    }
}

// ---------------- final dw3 + add -> global (coalesced along l) --------------
DEVI void dw3_glob(u16* sh, int inSlot, int addSlot, const float* W, const float* B,
                   float* outg, int b, int l0) {
    const int tid = threadIdx.x;
    #pragma unroll
    for (int k = 0; k < 8; ++k) {
        const int idx = tid + k * NTHR;         // 4096 = 64 chans x 64 pos
        const int c   = idx >> 6;
        const int e   = 12 + (idx & 63);
        const u16* si = sh + inSlot * SLOT + c;
        float acc = B[c];
        acc = fmaf(W[c * 3 + 0], bf2f(si[(e - 1) * RS]), acc);
        acc = fmaf(W[c * 3 + 1], bf2f(si[e * RS]), acc);
        acc = fmaf(W[c * 3 + 2], bf2f(si[(e + 1) * RS]), acc);
        acc += bf2f(sh[addSlot * SLOT + e * RS + c]);
        outg[((size_t)b * 256 + c) * 4096 + (l0 + e)] = acc;
    }
}

// ============================================================================

enum {
    I_X = 0, I_LN1W, I_LN1B, I_A1PW, I_A1PB, I_A1DW, I_A1DB, I_V1W, I_V1B,
    I_V11W, I_V11B, I_V12W, I_V12B, I_C31W, I_C31B,
    I_LN2W, I_LN2B, I_A2PW, I_A2PB, I_A2DW, I_A2DB, I_V2W, I_V2B,
    I_V21W, I_V21B, I_V22W, I_V22B, I_P2W, I_P2B, I_C32W, I_C32B,
    I_LN3W, I_LN3B, I_A3PW, I_A3PB, I_A3DW, I_A3DB, I_V3W, I_V3B,
    I_V31W, I_V31B, I_V32W, I_V32B, I_P3W, I_P3B, I_C33W, I_C33B
};
enum { W_A1P = 0, W_V1, W_V11, W_V12, W_A2P, W_V2, W_V21, W_V22, W_P2,
       W_A3P, W_V3, W_V31, W_V32, W_P3, W_N };

struct KArgs {
    const float* p[47]; const u16* w[W_N]; const float* stats;
    const float* uvA2; const float* uvV2; const float* uvA3; const float* uvV3;
    float* out;
};
struct CvtArgs {
    const float* src[W_N]; const float* scl[W_N]; u16* dst;
    int off[W_N + 1]; int cdim[W_N];
};
struct UVArgs {
    const float *w2a, *w2b, *b2a, *b2b, *ln2b;
    const float *w3a, *w3b, *b3a, *b3b, *ln3b;
    const u16 *f2a, *f2b, *f3a, *f3b;
    float *uvA2, *uvV2, *uvA3, *uvV3;
};

__global__ __launch_bounds__(256) void cvt_kernel(CvtArgs a) {
    const int i = blockIdx.x * 256 + threadIdx.x;
    if (i >= a.off[W_N]) return;
    int s = 0;
    while (i >= a.off[s + 1]) ++s;
    const int j = i - a.off[s];
    float v = a.src[s][j];
    if (a.scl[s]) {                            // fold LN weight into pw weight
        const int cd = a.cdim[s];
        v *= a.scl[s][j - (j / cd) * cd];
    }
    a.dst[i] = f2bf(v);
}

// u_o = pwb_o + (W @ ln_b)_o ; v_o = rowsum(bf16-folded W') — wave per output.
__global__ __launch_bounds__(64) void uv_kernel(UVArgs a) {
    const int blk  = blockIdx.x;               // 640 = 128+128+192+192
    const int lane = threadIdx.x;
    int o, C; const float *row, *lnb; const u16 *fr; float bias;
    float *uo, *vo;
    if (blk < 128) {
        o = blk; C = 128; row = a.w2a + (size_t)o * 128; lnb = a.ln2b;
        fr = a.f2a + (size_t)o * 128; bias = a.b2a[o];
        uo = a.uvA2 + o; vo = a.uvA2 + 128 + o;
    } else if (blk < 256) {
        o = blk - 128; C = 128; row = a.w2b + (size_t)o * 128; lnb = a.ln2b;
        fr = a.f2b + (size_t)o * 128; bias = a.b2b[o];
        uo = a.uvV2 + o; vo = a.uvV2 + 128 + o;
    } else if (blk < 448) {
        o = blk - 256; C = 192; row = a.w3a + (size_t)o * 192; lnb = a.ln3b;
        fr = a.f3a + (size_t)o * 192; bias = a.b3a[o];
        uo = a.uvA3 + o; vo = a.uvA3 + 192 + o;
    } else {
        o = blk - 448; C = 192; row = a.w3b + (size_t)o * 192; lnb = a.ln3b;
        fr = a.f3b + (size_t)o * 192; bias = a.b3b[o];
        uo = a.uvV3 + o; vo = a.uvV3 + 192 + o;
    }
    float u = 0.f, v = 0.f;
    for (int c = lane; c < C; c += 64) { u += row[c] * lnb[c]; v += bf2f(fr[c]); }
    #pragma unroll
    for (int off = 32; off; off >>= 1) {
        u += __shfl_down(u, off);
        v += __shfl_down(v, off);
    }
    if (lane == 0) { *uo = bias + u; *vo = v; }
}

// LN1 statistics for all (b,l): 256 thr = 64 l x 4 c-groups, LDS reduce.
// Cuts the stride-16KB serial load chain 4x vs one-thread-per-l.
__global__ __launch_bounds__(256) void ln1pre_kernel(const float* x, float* stats) {
    __shared__ float red[512];
    const int b    = blockIdx.x >> 6;          // 64 l-blocks of 64 per batch
    const int lb   = blockIdx.x & 63;
    const int lidx = threadIdx.x & 63;
    const int cg   = threadIdx.x >> 6;         // 0..3 (64 chans each)
    const int l    = lb * 64 + lidx;
    const float* p = x + ((size_t)b * 256 + cg * 64) * 4096 + l;
    float sm = 0.f, sq = 0.f;
    #pragma unroll 8
    for (int c = 0; c < 64; ++c) {
        const float v = p[(size_t)c * 4096];
        sm += v; sq += v * v;
    }
    red[threadIdx.x * 2]     = sm;
    red[threadIdx.x * 2 + 1] = sq;
    __syncthreads();
    if (threadIdx.x < 64) {
        float s = 0.f, q = 0.f;
        #pragma unroll
        for (int g = 0; g < 4; ++g) {
            s += red[(g * 64 + lidx) * 2];
            q += red[(g * 64 + lidx) * 2 + 1];
        }
        const float mu = s * (1.0f / 256.0f);
        const float va = q * (1.0f / 256.0f) - mu * mu;
        float2 o; o.x = mu; o.y = rsqrtf(va + 1e-6f);
        *(float2*)(stats + 2 * ((size_t)b * 4096 + l)) = o;
    }
}

__global__ __launch_bounds__(NTHR, 4) void convmod_kernel(KArgs a) {
    __shared__ u16 pool[6 * SLOT];                       // 76032 B
    __shared__ float meanA[EXT], rstdA[EXT], muRSB[EXT], rsB[EXT];
    __shared__ float scr[448];

    const int b    = blockIdx.x >> 6;
    const int tile = blockIdx.x & 63;
    const int l0   = tile * TL - 12;
    const float* xg = a.p[I_X];
    u16* sh = pool;

    // pre: LN1 stats from workspace
    if (threadIdx.x < EXT) {
        const int l = l0 + (int)threadIdx.x;
        float mu = 0.f, rs = 1.f;
        if ((unsigned)l < 4096u) {
            const float2 st = *(const float2*)(a.stats + 2 * ((size_t)b * 4096 + l));
            mu = st.x; rs = st.y;
        }
        meanA[threadIdx.x] = mu; rstdA[threadIdx.x] = rs;
    }
    __syncthreads();
    // P0
    norm_load(sh, 0, xg, b,  0, a.p[I_LN1W], a.p[I_LN1B], meanA, rstdA, 0, EXT, l0);
    norm_load(sh, 1, xg, b, 64, a.p[I_LN1W], a.p[I_LN1B], meanA, rstdA, 0, EXT, l0);
    __syncthreads();
    // P1: merged g1|pv1 (S0 -> S2,S3), pwv12 (S1 -> S4)
    pw_mfma<128, 64, 64, true, false, false, false>(sh, SL{0,-1,-1}, SL{2,-1,-1}, SL{3,-1,-1},
        a.w[W_A1P], a.p[I_A1PB], a.p[I_V1B], 0, 88, l0);
    pw_mfma<64, 64, 64, false, false, false, false>(sh, SL{1,-1,-1}, SL{4,-1,-1}, SL{4,-1,-1},
        a.w[W_V12], a.p[I_V12B], a.p[I_V12B], 2, 86, l0);
    __syncthreads();
    // P2: a1 -> S5, t1 = a1*pv1 in-place S3
    dw_mul<64, 7, 3, 16, false>(sh, SL{2,-1,-1}, SL{5,-1,-1}, SL{3,-1,-1}, a.p[I_A1DW], a.p[I_A1DB], 3, 85);
    __syncthreads();
    // P3: mul1 -> S2, x1low = dw3(S4)+S5 -> S1
    pw_mfma<64, 64, 64, false, false, false, false>(sh, SL{3,-1,-1}, SL{2,-1,-1}, SL{2,-1,-1},
        a.w[W_V11], a.p[I_V11B], a.p[I_V11B], 3, 85, l0);
    dw_ph<64, 3, 1, 11, true>(sh, SL{4,-1,-1}, SL{5,-1,-1}, SL{1,-1,-1}, a.p[I_C31W], a.p[I_C31B], 3, 85, l0);
    __syncthreads();
    // P4: ln2 STATS over raw {S1,S2}
    ln_stats<128>(sh, SL{1,2,-1}, 3, 85, scr, muRSB, rsB);
    __syncthreads();
    // P5: xs2n -> S0; g2 LNF {S1,S2}->{S3,S4}; pv2 LNF INPL {S1,S2}
    norm_load(sh, 0, xg, b, 128, a.p[I_LN1W], a.p[I_LN1B], meanA, rstdA, 6, 82, l0);
    pw_mfma<128, 128, 128, true, false, false, true>(sh, SL{1,2,-1}, SL{3,4,-1}, SL{3,4,-1},
        a.w[W_A2P], nullptr, nullptr, 3, 85, l0, a.uvA2, rsB, muRSB);
    pw_mfma<128, 128, 128, false, false, true, true>(sh, SL{1,2,-1}, SL{1,2,-1}, SL{1,2,-1},
        a.w[W_V2], nullptr, nullptr, 7, 81, l0, a.uvV2, rsB, muRSB);
    __syncthreads();
    // P6: pwv22 S0 -> S5, a2 = dw9 INPL {S3,S4} + t2 in-place {S1,S2}
    pw_mfma<64, 64, 64, false, false, false, false>(sh, SL{0,-1,-1}, SL{5,-1,-1}, SL{5,-1,-1},
        a.w[W_V22], a.p[I_V22B], a.p[I_V22B], 6, 82, l0);
    dw_mul<128, 9, 4, 19, true>(sh, SL{3,4,-1}, SL{3,4,-1}, SL{1,2,-1}, a.p[I_A2DW], a.p[I_A2DB], 7, 81);
    __syncthreads();
    // P7: p2a {S3,S4} -> S0, mul2 INPL {S1,S2}
    pw_mfma<64, 128, 64, false, false, false, false>(sh, SL{3,4,-1}, SL{0,-1,-1}, SL{0,-1,-1},
        a.w[W_P2], a.p[I_P2B], a.p[I_P2B], 7, 81, l0);
    pw_mfma<128, 128, 128, false, false, true, false>(sh, SL{1,2,-1}, SL{1,2,-1}, SL{1,2,-1},
        a.w[W_V21], a.p[I_V21B], a.p[I_V21B], 7, 81, l0);
    __syncthreads();
    // P8: x2low = dw3(S5)+S0 -> S3
    dw_ph<64, 3, 1, 10, true>(sh, SL{5,-1,-1}, SL{0,-1,-1}, SL{3,-1,-1}, a.p[I_C32W], a.p[I_C32B], 7, 81, l0);
    __syncthreads();
    // P9: ln3 STATS over raw {S3,S1,S2}
    ln_stats<192>(sh, SL{3,1,2}, 7, 81, scr, muRSB, rsB);
    __syncthreads();
    // P10: g3 LNF {S3,S1,S2}->{S4,S5,S0}; pv3 LNF INPL {S3,S1,S2}
    pw_mfma<192, 192, 192, true, false, false, true>(sh, SL{3,1,2}, SL{4,5,0}, SL{4,5,0},
        a.w[W_A3P], nullptr, nullptr, 7, 81, l0, a.uvA3, rsB, muRSB);
    pw_mfma<192, 192, 192, false, false, true, true>(sh, SL{3,1,2}, SL{3,1,2}, SL{3,1,2},
        a.w[W_V3], nullptr, nullptr, 12, 76, l0, a.uvV3, rsB, muRSB);
    __syncthreads();
    // P11: a3 = dw11 INPL {S4,S5,S0} + t3 in-place {S3,S1,S2}
    dw_mul<192, 11, 5, 32, true>(sh, SL{4,5,0}, SL{4,5,0}, SL{3,1,2}, a.p[I_A3DW], a.p[I_A3DB], 12, 76);
    __syncthreads();
    // P12: mul3 -> out[64:256], p3a INPL {S4,S5,S0} -> S4, xs3n -> S5
    pw_mfma<192, 192, 192, false, true, false, false>(sh, SL{3,1,2}, SL{-1,-1,-1}, SL{-1,-1,-1},
        a.w[W_V31], a.p[I_V31B], a.p[I_V31B], 12, 76, l0,
        nullptr, nullptr, nullptr, a.out, b, 64);
    pw_mfma<64, 192, 64, false, false, true, false>(sh, SL{4,5,0}, SL{4,-1,-1}, SL{4,-1,-1},
        a.w[W_P3], a.p[I_P3B], a.p[I_P3B], 12, 76, l0);
    norm_load(sh, 5, xg, b, 192, a.p[I_LN1W], a.p[I_LN1B], meanA, rstdA, 11, 77, l0);
    __syncthreads();
    // P13: pwv32 S5 -> S0
    pw_mfma<64, 64, 64, false, false, false, false>(sh, SL{5,-1,-1}, SL{0,-1,-1}, SL{0,-1,-1},
        a.w[W_V32], a.p[I_V32B], a.p[I_V32B], 11, 77, l0);
    __syncthreads();
    // P14: x3 = dw3(S0)+S4 -> out[0:64]
    dw3_glob(sh, 0, 4, a.p[I_C33W], a.p[I_C33B], a.out, b, l0);
}

extern "C" void kernel_launch(void* const* d_in, const int* in_sizes, int n_in,
                              void* d_out, int out_size, void* d_ws, size_t ws_size,
                              hipStream_t stream) {
    (void)in_sizes; (void)n_in; (void)out_size; (void)ws_size;
    static const int widx[W_N] = { I_A1PW, I_V1W, I_V11W, I_V12W, I_A2PW, I_V2W,
                                   I_V21W, I_V22W, I_P2W, I_A3PW, I_V3W, I_V31W,
                                   I_V32W, I_P3W };
    static const int wsz[W_N]  = { 4096, 4096, 4096, 4096, 16384, 16384, 16384,
                                   4096, 8192, 36864, 36864, 36864, 4096, 12288 };
    static const int wcd[W_N]  = { 64, 64, 64, 64, 128, 128, 128, 64, 128,
                                   192, 192, 192, 64, 192 };
    CvtArgs ca; KArgs ka;
    int off = 0;
    for (int i = 0; i < W_N; ++i) {
        ca.src[i]  = (const float*)d_in[widx[i]];
        ca.scl[i]  = nullptr;
        ca.cdim[i] = wcd[i];
        ca.off[i]  = off;
        off += wsz[i];
    }
    // fold LN2/LN3 scale into the LNF-consumed weight blobs
    ca.scl[W_A2P] = (const float*)d_in[I_LN2W];
    ca.scl[W_V2]  = (const float*)d_in[I_LN2W];
    ca.scl[W_A3P] = (const float*)d_in[I_LN3W];
    ca.scl[W_V3]  = (const float*)d_in[I_LN3W];
    ca.off[W_N] = off;                       // 204800 elems = 409600 B in d_ws
    ca.dst = (u16*)d_ws;
    for (int i = 0; i < 47; ++i) ka.p[i] = (const float*)d_in[i];
    for (int i = 0; i < W_N; ++i) ka.w[i] = (const u16*)d_ws + ca.off[i];
    // workspace: weights | LN1 stats (1 MiB) | uvA2(256f) uvV2(256f) uvA3(384f) uvV3(384f)
    const size_t stats_off = ((size_t)off * sizeof(u16) + 255) & ~(size_t)255;
    float* stats = (float*)((char*)d_ws + stats_off);
    float* uvA2  = stats + (size_t)32 * 4096 * 2;
    float* uvV2  = uvA2 + 256;
    float* uvA3  = uvV2 + 256;
    float* uvV3  = uvA3 + 384;
    ka.stats = stats;
    ka.uvA2 = uvA2; ka.uvV2 = uvV2; ka.uvA3 = uvA3; ka.uvV3 = uvV3;
    ka.out = (float*)d_out;

    UVArgs ua;
    ua.w2a = (const float*)d_in[I_A2PW]; ua.w2b = (const float*)d_in[I_V2W];
    ua.b2a = (const float*)d_in[I_A2PB]; ua.b2b = (const float*)d_in[I_V2B];
    ua.ln2b = (const float*)d_in[I_LN2B];
    ua.w3a = (const float*)d_in[I_A3PW]; ua.w3b = (const float*)d_in[I_V3W];
    ua.b3a = (const float*)d_in[I_A3PB]; ua.b3b = (const float*)d_in[I_V3B];
    ua.ln3b = (const float*)d_in[I_LN3B];
    ua.f2a = (const u16*)d_ws + ca.off[W_A2P];
    ua.f2b = (const u16*)d_ws + ca.off[W_V2];
    ua.f3a = (const u16*)d_ws + ca.off[W_A3P];
    ua.f3b = (const u16*)d_ws + ca.off[W_V3];
    ua.uvA2 = uvA2; ua.uvV2 = uvV2; ua.uvA3 = uvA3; ua.uvV3 = uvV3;

    cvt_kernel<<<dim3((off + 255) / 256), dim3(256), 0, stream>>>(ca);
    uv_kernel<<<dim3(640), dim3(64), 0, stream>>>(ua);
    ln1pre_kernel<<<dim3(32 * 64), dim3(256), 0, stream>>>((const float*)d_in[I_X], stats);
    convmod_kernel<<<dim3(32 * 64), dim3(NTHR), 0, stream>>>(ka);
}

// Round 9
// 663.468 us; speedup vs baseline: 1.0471x; 1.0471x over previous
//
#include <hip/hip_runtime.h>
#include <cmath>

// ============================================================================
// ConvMod1D fused kernel — round 9: r7 convmod (397us, verified) minus the
// r8 setprio regression (+5% — m190-style null: barrier-locked phases give
// the scheduler nothing to arbitrate), plus T14 issue-early/write-late for
// the two mid-kernel x-loads, plus r8's fast aux kernels (kept; −18us).
//   xs2n: issue @P2 start, write S0 @P2 end (HBM latency hides under dw_mul
//         a1; S0 dead P2..P6; also shortens P5, the fattest MFMA phase).
//   xs3n: issue @P12 start, write S5 after p3a's internal barrier (latency
//         hides under mul3+p3a k-loops; write position unchanged vs r7).
// TL=64 (halo 12 -> EXT=88), 512 thr, 6 LDS slots RS=72 -> 76.0 KB =>
// 2 blocks/CU. Wave grid 4Mx2N, NT=3 BLOCKED. LN folding (r7):
//   pw(LN(x)) = rs_e*(W'@x_raw) + (u_o - muRS_e*v_o);  W' = W*diag(ln_w).
//
// Slot schedule (S0..S5; stale data only feeds masked cols / finite bf16):
//  pre: meanA/rstdA <- stats | P0 xs0n->S0, xs1n->S1 [0,88)
//  P1 g1pv1: S0 -> g1:S2, pv1:S3 [0,88); pwv12: S1->S4 [2,86)
//  P2 xs2n issue; a1=dw7(S2)->S5 + t1=a1*pv1 in-place S3 [3,85); xs2n->S0 [6,82)
//  P3 mul1=pw(S3)->S2, x1low=dw3(S4)+S5->S1    [3,85)
//  P4 ln2 STATS over raw {S1,S2} [3,85) -> rsB, muRSB
//  P5 g2(LNF):{S1,S2}->{S3,S4} [3,85); pv2(LNF,INPL):{S1,S2}->{S1,S2} [7,81)
//  P6 pwv22: S0->S5 [6,82), a2=dw9 INPL {S3,S4} + t2 in-place {S1,S2} [7,81)
//  P7 p2a: {S3,S4}->S0 [7,81), mul2 INPL {S1,S2} [7,81)
//  P8 x2low=dw3(S5)+S0->S3 [7,81)
//  P9 ln3 STATS over raw {S3,S1,S2} [7,81)
//  P10 g3(LNF):{S3,S1,S2}->{S4,S5,S0} [7,81);
//      pv3(LNF,INPL):{S3,S1,S2}->{S3,S1,S2} [12,76)
//  P11 a3=dw11 INPL {S4,S5,S0} + t3 in-place {S3,S1,S2} [12,76)
//  P12 xs3n issue; mul3: pw(t3)->OUT[64:256] [12,76); p3a INPL {S4,S5,S0}->S4;
//      xs3n->S5 [11,77)
//  P13 pwv32: S5->S0 [11,77)
//  P14 x3=dw3(S0)+S4->OUT[0:64] [12,76)
// ============================================================================

using u16 = unsigned short;
typedef short shrt8 __attribute__((ext_vector_type(8)));
typedef short shrt4 __attribute__((ext_vector_type(4)));
typedef float f32x4 __attribute__((ext_vector_type(4)));

#define DEVI __device__ __forceinline__

static constexpr int TL   = 64;          // useful positions per block
static constexpr int EXT  = 88;          // 64 useful + 2*12 halo
static constexpr int RS   = 72;          // row stride in u16 (64 + 8 pad)
static constexpr int SLOT = EXT * RS;    // 6336 u16 = 12672 B
static constexpr int NW   = 8;
static constexpr int NTHR = 512;

DEVI u16 f2bf(float f) {                 // RNE fp32 -> bf16
    unsigned u = __float_as_uint(f);
    u += 0x7FFFu + ((u >> 16) & 1u);
    return (u16)(u >> 16);
}
DEVI float bf2f(u16 h) { return __uint_as_float(((unsigned)h) << 16); }

// exact-GELU via Abramowitz-Stegun 7.1.26 erf (|err| <= 1.5e-7, branch-free)
DEVI float gelu_f(float x) {
    const float y  = x * 0.70710678118654752f;
    const float ay = fabsf(y);
    const float t  = __builtin_amdgcn_rcpf(fmaf(0.3275911f, ay, 1.0f));
    float p = 1.061405429f;
    p = fmaf(p, t, -1.453152027f);
    p = fmaf(p, t,  1.421413741f);
    p = fmaf(p, t, -0.284496736f);
    p = fmaf(p, t,  0.254829592f);
    float er = 1.0f - p * t * __expf(-ay * ay);
    er = copysignf(er, y);
    return 0.5f * x * (1.0f + er);
}

struct SL { int a, b, c; };
DEVI int slotOf(SL s, int ch) { return ch < 64 ? s.a : (ch < 128 ? s.b : s.c); }

// ---------------- pointwise conv via MFMA ------------------------------------
// Wave grid 4M x 2N; NT=3 BLOCKED n-tiles/wave (nt = nw*3 + ni).
// ch<OSPLIT -> outA (optional GELU, biasA); ch>=OSPLIT -> outB (biasB).
// Wb is [O,C] row-major. INPL: out aliases in -> barrier between k-loop and
// store. LNF: val = rs_e*acc + (u_ch - muRS_e*v_ch), uv = [u[0..O)|v[0..O)].
template<int O, int C, int OSPLIT, bool GELU, bool TOG, bool INPL, bool LNF>
DEVI void pw_mfma(u16* sh, SL in, SL outA, SL outB, const u16* Wb,
                  const float* biasA, const float* biasB,
                  int elo, int ehi, int l0,
                  const float* uv = nullptr, const float* rsA = nullptr,
                  const float* mrsA = nullptr,
                  float* outg = nullptr, int bidx = 0, int ochan = 0) {
    constexpr int MR = O / 64;           // m-tiles per wave (4 m-waves)
    constexpr int KT = C / 32;
    constexpr int NT = 3;
    const int lane = threadIdx.x & 63;
    const int wv   = threadIdx.x >> 6;
    const int mw = wv >> 1, nw = wv & 1;
    const int col  = lane & 15;
    const int quad = lane >> 4;
    const int mrow = mw * (MR * 16) + col;
    const int kq   = quad * 8;
    const int crow = mw * (MR * 16) + quad * 4;

    f32x4 acc[MR][NT];
    #pragma unroll
    for (int mi = 0; mi < MR; ++mi) {
        f32x4 bv;
        if (LNF) { bv[0] = 0.f; bv[1] = 0.f; bv[2] = 0.f; bv[3] = 0.f; }
        else {
            const int ch = crow + mi * 16;
            const float* bp = (OSPLIT < O && ch >= OSPLIT) ? (biasB + (ch - OSPLIT))
                                                           : (biasA + ch);
            bv = *(const f32x4*)bp;
        }
        #pragma unroll
        for (int ni = 0; ni < NT; ++ni) acc[mi][ni] = bv;
    }
    bool act[NT]; int bpos[NT];
    #pragma unroll
    for (int ni = 0; ni < NT; ++ni) {
        const int nt = nw * NT + ni;
        act[ni] = (nt * 16 < ehi) && (nt * 16 + 16 > elo);
        int p = nt * 16 + col; if (p > EXT - 1) p = EXT - 1;  // masked cols only
        bpos[ni] = p;
    }
    #pragma unroll
    for (int kt = 0; kt < KT; ++kt) {
        shrt8 af[MR];
        #pragma unroll
        for (int mi = 0; mi < MR; ++mi)
            af[mi] = *(const shrt8*)(Wb + (size_t)(mrow + mi * 16) * C + kt * 32 + kq);
        const int k0 = kt * 32;
        const u16* bs = sh + slotOf(in, k0) * SLOT + ((k0 & 63) + kq);
        #pragma unroll
        for (int ni = 0; ni < NT; ++ni) {
            if (!act[ni]) continue;
            const shrt8 bf = *(const shrt8*)(bs + bpos[ni] * RS);
            #pragma unroll
            for (int mi = 0; mi < MR; ++mi)
                acc[mi][ni] = __builtin_amdgcn_mfma_f32_16x16x32_bf16(af[mi], bf, acc[mi][ni], 0, 0, 0);
        }
    }
    if (INPL) __syncthreads();           // all reads done before any store
    float rsv[NT], mrsv[NT];
    if (LNF) {
        #pragma unroll
        for (int ni = 0; ni < NT; ++ni) {
            rsv[ni]  = rsA[bpos[ni]];    // clamped pos: garbage only feeds masked stores
            mrsv[ni] = mrsA[bpos[ni]];
        }
    }
    #pragma unroll
    for (int mi = 0; mi < MR; ++mi) {
        const int ch = crow + mi * 16;
        const bool isA = !(OSPLIT < O) || (ch < OSPLIT);
        f32x4 u4, v4;
        if (LNF) {
            u4 = *(const f32x4*)(uv + ch);
            v4 = *(const f32x4*)(uv + O + ch);
        }
        #pragma unroll
        for (int ni = 0; ni < NT; ++ni) {
            if (!act[ni]) continue;
            const int e = (nw * NT + ni) * 16 + col;
            if (e < elo || e >= ehi) continue;
            const int l = l0 + e;
            f32x4 v = acc[mi][ni];
            if (LNF) {
                #pragma unroll
                for (int i = 0; i < 4; ++i)
                    v[i] = fmaf(rsv[ni], v[i], fmaf(-mrsv[ni], v4[i], u4[i]));
            }
            if (GELU && isA) { v[0]=gelu_f(v[0]); v[1]=gelu_f(v[1]); v[2]=gelu_f(v[2]); v[3]=gelu_f(v[3]); }
            if (TOG) {
                float* og = outg + ((size_t)bidx * 256 + ochan + ch) * 4096 + l;
                og[0] = v[0]; og[4096] = v[1]; og[2*4096] = v[2]; og[3*4096] = v[3];
            } else {
                const int cl = isA ? ch : ch - OSPLIT;
                const SL  os = isA ? outA : outB;
                const bool gv = (unsigned)l < 4096u;
                shrt4 pk;
                pk[0] = gv ? (short)f2bf(v[0]) : (short)0;
                pk[1] = gv ? (short)f2bf(v[1]) : (short)0;
                pk[2] = gv ? (short)f2bf(v[2]) : (short)0;
                pk[3] = gv ? (short)f2bf(v[3]) : (short)0;
                *(shrt4*)(sh + slotOf(os, cl) * SLOT + e * RS + (cl & 63)) = pk;
            }
        }
    }
}

// ---------------- depthwise conv fused with t = a*v, optional in-place -------
// One window of WIN positions per wave (tasks = (C/64)*nwin must be <= NW).
template<int C, int K, int PAD, int WIN, bool INPL>
DEVI void dw_mul(u16* sh, SL g, SL ao, SL v, const float* W, const float* bias,
                 int elo, int ehi) {
    const int lane = threadIdx.x & 63;
    const int wv   = threadIdx.x >> 6;
    const int nwin  = (ehi - elo + WIN - 1) / WIN;
    const int tasks = (C / 64) * nwin;       // <= NW by construction
    const bool have = wv < tasks;
    float r[K + WIN - 1];
    float wk[K];
    float bo = 0.f;
    int c = 0, e0 = 0;
    if (have) {
        const int cb = wv / nwin, wi = wv - cb * nwin;
        c = cb * 64 + lane;
        #pragma unroll
        for (int k = 0; k < K; ++k) wk[k] = W[c * K + k];
        bo = bias[c];
        e0 = elo + wi * WIN;
        const u16* si = sh + slotOf(g, c) * SLOT + lane;
        #pragma unroll
        for (int m = 0; m < K + WIN - 1; ++m) {
            int e = e0 - PAD + m; if (e > EXT - 1) e = EXT - 1;  // feeds masked outputs only
            r[m] = bf2f(si[e * RS]);
        }
    }
    if (INPL) __syncthreads();               // all reads done before any write
    if (have) {
        u16* sa = sh + slotOf(ao, c) * SLOT + lane;
        u16* sv = sh + slotOf(v, c) * SLOT + lane;
        #pragma unroll
        for (int j = 0; j < WIN; ++j) {
            const int e = e0 + j;
            if (e >= ehi) break;
            float acc = bo;
            #pragma unroll
            for (int k = 0; k < K; ++k) acc = fmaf(wk[k], r[j + k], acc);
            sa[e * RS] = f2bf(acc);                               // a
            sv[e * RS] = f2bf(acc * bf2f(sv[e * RS]));            // t = a*v (v masked 0 OOB)
        }
    }
}

// ---------------- depthwise conv (VALU), chan-per-lane, WIN-pos windows ------
template<int C, int K, int PAD, int WIN, bool ADD>
DEVI void dw_ph(u16* sh, SL in, SL add, SL out, const float* W, const float* bias,
                int elo, int ehi, int l0) {
    const int lane = threadIdx.x & 63;
    const int wv   = threadIdx.x >> 6;
    const int nwin = (ehi - elo + WIN - 1) / WIN;
    const int tasks = (C / 64) * nwin;
    for (int t = wv; t < tasks; t += NW) {
        const int cb = t / nwin, wi = t - cb * nwin;
        const int c = cb * 64 + lane;
        float wk[K];
        #pragma unroll
        for (int k = 0; k < K; ++k) wk[k] = W[c * K + k];
        const float bo = bias[c];
        const int e0 = elo + wi * WIN;
        const u16* si = sh + slotOf(in, c) * SLOT + lane;
        const u16* sa = ADD ? (sh + slotOf(add, c) * SLOT + lane) : nullptr;
        u16* so = sh + slotOf(out, c) * SLOT + lane;
        float r[K + WIN - 1];
        #pragma unroll
        for (int m = 0; m < K + WIN - 1; ++m) {
            int e = e0 - PAD + m; if (e > EXT - 1) e = EXT - 1;  // feeds masked outputs only
            r[m] = bf2f(si[e * RS]);
        }
        #pragma unroll
        for (int j = 0; j < WIN; ++j) {
            const int e = e0 + j;
            if (e >= ehi) break;
            float acc = bo;
            #pragma unroll
            for (int k = 0; k < K; ++k) acc = fmaf(wk[k], r[j + k], acc);
            if (ADD) acc += bf2f(sa[e * RS]);
            const bool gv = (unsigned)(l0 + e) < 4096u;
            so[e * RS] = gv ? f2bf(acc) : (u16)0;
        }
    }
}

// ---------------- LayerNorm statistics only (values stay RAW in LDS) ---------
// Writes rs[e] = rstd_e and muRS[e] = mu_e * rstd_e for e in [elo,ehi).
template<int C>
DEVI void ln_stats(u16* sh, SL s, int elo, int ehi, float* scr,
                   float* muRS, float* rs) {
    constexpr int P = C / 64;
    const int tid = threadIdx.x;
    const int nP = ehi - elo;
    if (tid < nP * P) {
        const int e = elo + tid / P;
        const int part = tid - (tid / P) * P;
        const u16* row = sh + slotOf(s, part * 64) * SLOT + e * RS;
        float sm = 0.f, sq = 0.f;
        #pragma unroll
        for (int j = 0; j < 8; ++j) {
            shrt8 v = *(const shrt8*)(row + j * 8);
            #pragma unroll
            for (int i = 0; i < 8; ++i) { float f = bf2f((u16)v[i]); sm += f; sq += f * f; }
        }
        scr[tid * 2] = sm; scr[tid * 2 + 1] = sq;
    }
    __syncthreads();
    if (tid < nP) {
        float sm = 0.f, sq = 0.f;
        for (int p = 0; p < P; ++p) { sm += scr[(tid * P + p) * 2]; sq += scr[(tid * P + p) * 2 + 1]; }
        const float mu = sm * (1.0f / C);
        const float va = sq * (1.0f / C) - mu * mu;
        const float r = rsqrtf(va + 1e-6f);
        rs[elo + tid] = r; muRS[elo + tid] = mu * r;
    }
}

// ---------------- load 64-chan chunk of x, apply LN1, store bf16 -------------
DEVI void norm_load(u16* sh, int slot, const float* xg, int b, int cbase,
                    const float* lnw, const float* lnb,
                    const float* mean, const float* rstd,
                    int elo, int ehi, int l0) {
    const int lane = threadIdx.x & 63;
    const int wv   = threadIdx.x >> 6;
    #pragma unroll
    for (int j = 0; j < 8; ++j) {
        const int o = wv + NW * j;
        const float* p = xg + ((size_t)b * 256 + cbase + o) * 4096;
        const float wo = lnw[cbase + o], bo = lnb[cbase + o];
        u16* r = sh + slot * SLOT + o;
        #pragma unroll
        for (int part = 0; part < 2; ++part) {
            const int e = elo + lane + part * 64;
            if (e < ehi) {
                const int l = l0 + e;
                const bool gv = (unsigned)l < 4096u;
                float v = gv ? p[l] : 0.f;
                v = (v - mean[e]) * rstd[e] * wo + bo;
                r[e * RS] = gv ? f2bf(v) : (u16)0;
            }
        }
    }
}

// ---- T14 split: issue x loads into regs early; write+normalize late ---------
DEVI void nl_issue(float* xr, const float* xg, int b, int cbase,
                   int elo, int ehi, int l0) {
    const int lane = threadIdx.x & 63;
    const int wv   = threadIdx.x >> 6;
    #pragma unroll
    for (int j = 0; j < 8; ++j) {
        const int o = wv + NW * j;
        const float* p = xg + ((size_t)b * 256 + cbase + o) * 4096;
        #pragma unroll
        for (int part = 0; part < 2; ++part) {
            const int e = elo + lane + part * 64;
            const int l = l0 + e;
            xr[j * 2 + part] = (e < ehi && (unsigned)l < 4096u) ? p[l] : 0.f;
        }
    }
}
DEVI void nl_write(u16* sh, int slot, const float* xr, int cbase,
                   const float* lnw, const float* lnb,
                   const float* mean, const float* rstd,
                   int elo, int ehi, int l0) {
    const int lane = threadIdx.x & 63;
    const int wv   = threadIdx.x >> 6;
    #pragma unroll
    for (int j = 0; j < 8; ++j) {
        const int o = wv + NW * j;
        const float wo = lnw[cbase + o], bo = lnb[cbase + o];
        u16* r = sh + slot * SLOT + o;
        #pragma unroll
        for (int part = 0; part < 2; ++part) {
            const int e = elo + lane + part * 64;
            if (e < ehi) {
                const int l = l0 + e;
                const bool gv = (unsigned)l < 4096u;
                float v = (xr[j * 2 + part] - mean[e]) * rstd[e] * wo + bo;
                r[e * RS] = gv ? f2bf(v) : (u16)0;
            }
        }
    }
}

// ---------------- final dw3 + add -> global (coalesced along l) --------------
DEVI void dw3_glob(u16* sh, int inSlot, int addSlot, const float* W, const float* B,
                   float* outg, int b, int l0) {
    const int tid = threadIdx.x;
    #pragma unroll
    for (int k = 0; k < 8; ++k) {
        const int idx = tid + k * NTHR;         // 4096 = 64 chans x 64 pos
        const int c   = idx >> 6;
        const int e   = 12 + (idx & 63);
        const u16* si = sh + inSlot * SLOT + c;
        float acc = B[c];
        acc = fmaf(W[c * 3 + 0], bf2f(si[(e - 1) * RS]), acc);
        acc = fmaf(W[c * 3 + 1], bf2f(si[e * RS]), acc);
        acc = fmaf(W[c * 3 + 2], bf2f(si[(e + 1) * RS]), acc);
        acc += bf2f(sh[addSlot * SLOT + e * RS + c]);
        outg[((size_t)b * 256 + c) * 4096 + (l0 + e)] = acc;
    }
}

// ============================================================================

enum {
    I_X = 0, I_LN1W, I_LN1B, I_A1PW, I_A1PB, I_A1DW, I_A1DB, I_V1W, I_V1B,
    I_V11W, I_V11B, I_V12W, I_V12B, I_C31W, I_C31B,
    I_LN2W, I_LN2B, I_A2PW, I_A2PB, I_A2DW, I_A2DB, I_V2W, I_V2B,
    I_V21W, I_V21B, I_V22W, I_V22B, I_P2W, I_P2B, I_C32W, I_C32B,
    I_LN3W, I_LN3B, I_A3PW, I_A3PB, I_A3DW, I_A3DB, I_V3W, I_V3B,
    I_V31W, I_V31B, I_V32W, I_V32B, I_P3W, I_P3B, I_C33W, I_C33B
};
enum { W_A1P = 0, W_V1, W_V11, W_V12, W_A2P, W_V2, W_V21, W_V22, W_P2,
       W_A3P, W_V3, W_V31, W_V32, W_P3, W_N };

struct KArgs {
    const float* p[47]; const u16* w[W_N]; const float* stats;
    const float* uvA2; const float* uvV2; const float* uvA3; const float* uvV3;
    float* out;
};
struct CvtArgs {
    const float* src[W_N]; const float* scl[W_N]; u16* dst;
    int off[W_N + 1]; int cdim[W_N];
};
struct UVArgs {
    const float *w2a, *w2b, *b2a, *b2b, *ln2b;
    const float *w3a, *w3b, *b3a, *b3b, *ln3b;
    const u16 *f2a, *f2b, *f3a, *f3b;
    float *uvA2, *uvV2, *uvA3, *uvV3;
};

__global__ __launch_bounds__(256) void cvt_kernel(CvtArgs a) {
    const int i = blockIdx.x * 256 + threadIdx.x;
    if (i >= a.off[W_N]) return;
    int s = 0;
    while (i >= a.off[s + 1]) ++s;
    const int j = i - a.off[s];
    float v = a.src[s][j];
    if (a.scl[s]) {                            // fold LN weight into pw weight
        const int cd = a.cdim[s];
        v *= a.scl[s][j - (j / cd) * cd];
    }
    a.dst[i] = f2bf(v);
}

// u_o = pwb_o + (W @ ln_b)_o ; v_o = rowsum(bf16-folded W') — wave per output.
__global__ __launch_bounds__(64) void uv_kernel(UVArgs a) {
    const int blk  = blockIdx.x;               // 640 = 128+128+192+192
    const int lane = threadIdx.x;
    int o, C; const float *row, *lnb; const u16 *fr; float bias;
    float *uo, *vo;
    if (blk < 128) {
        o = blk; C = 128; row = a.w2a + (size_t)o * 128; lnb = a.ln2b;
        fr = a.f2a + (size_t)o * 128; bias = a.b2a[o];
        uo = a.uvA2 + o; vo = a.uvA2 + 128 + o;
    } else if (blk < 256) {
        o = blk - 128; C = 128; row = a.w2b + (size_t)o * 128; lnb = a.ln2b;
        fr = a.f2b + (size_t)o * 128; bias = a.b2b[o];
        uo = a.uvV2 + o; vo = a.uvV2 + 128 + o;
    } else if (blk < 448) {
        o = blk - 256; C = 192; row = a.w3a + (size_t)o * 192; lnb = a.ln3b;
        fr = a.f3a + (size_t)o * 192; bias = a.b3a[o];
        uo = a.uvA3 + o; vo = a.uvA3 + 192 + o;
    } else {
        o = blk - 448; C = 192; row = a.w3b + (size_t)o * 192; lnb = a.ln3b;
        fr = a.f3b + (size_t)o * 192; bias = a.b3b[o];
        uo = a.uvV3 + o; vo = a.uvV3 + 192 + o;
    }
    float u = 0.f, v = 0.f;
    for (int c = lane; c < C; c += 64) { u += row[c] * lnb[c]; v += bf2f(fr[c]); }
    #pragma unroll
    for (int off = 32; off; off >>= 1) {
        u += __shfl_down(u, off);
        v += __shfl_down(v, off);
    }
    if (lane == 0) { *uo = bias + u; *vo = v; }
}

// LN1 statistics for all (b,l): 256 thr = 64 l x 4 c-groups, LDS reduce.
// Cuts the stride-16KB serial load chain 4x vs one-thread-per-l.
__global__ __launch_bounds__(256) void ln1pre_kernel(const float* x, float* stats) {
    __shared__ float red[512];
    const int b    = blockIdx.x >> 6;          // 64 l-blocks of 64 per batch
    const int lb   = blockIdx.x & 63;
    const int lidx = threadIdx.x & 63;
    const int cg   = threadIdx.x >> 6;         // 0..3 (64 chans each)
    const int l    = lb * 64 + lidx;
    const float* p = x + ((size_t)b * 256 + cg * 64) * 4096 + l;
    float sm = 0.f, sq = 0.f;
    #pragma unroll 8
    for (int c = 0; c < 64; ++c) {
        const float v = p[(size_t)c * 4096];
        sm += v; sq += v * v;
    }
    red[threadIdx.x * 2]     = sm;
    red[threadIdx.x * 2 + 1] = sq;
    __syncthreads();
    if (threadIdx.x < 64) {
        float s = 0.f, q = 0.f;
        #pragma unroll
        for (int g = 0; g < 4; ++g) {
            s += red[(g * 64 + lidx) * 2];
            q += red[(g * 64 + lidx) * 2 + 1];
        }
        const float mu = s * (1.0f / 256.0f);
        const float va = q * (1.0f / 256.0f) - mu * mu;
        float2 o; o.x = mu; o.y = rsqrtf(va + 1e-6f);
        *(float2*)(stats + 2 * ((size_t)b * 4096 + l)) = o;
    }
}

__global__ __launch_bounds__(NTHR, 4) void convmod_kernel(KArgs a) {
    __shared__ u16 pool[6 * SLOT];                       // 76032 B
    __shared__ float meanA[EXT], rstdA[EXT], muRSB[EXT], rsB[EXT];
    __shared__ float scr[448];

    const int b    = blockIdx.x >> 6;
    const int tile = blockIdx.x & 63;
    const int l0   = tile * TL - 12;
    const float* xg = a.p[I_X];
    u16* sh = pool;

    // pre: LN1 stats from workspace
    if (threadIdx.x < EXT) {
        const int l = l0 + (int)threadIdx.x;
        float mu = 0.f, rs = 1.f;
        if ((unsigned)l < 4096u) {
            const float2 st = *(const float2*)(a.stats + 2 * ((size_t)b * 4096 + l));
            mu = st.x; rs = st.y;
        }
        meanA[threadIdx.x] = mu; rstdA[threadIdx.x] = rs;
    }
    __syncthreads();
    // P0
    norm_load(sh, 0, xg, b,  0, a.p[I_LN1W], a.p[I_LN1B], meanA, rstdA, 0, EXT, l0);
    norm_load(sh, 1, xg, b, 64, a.p[I_LN1W], a.p[I_LN1B], meanA, rstdA, 0, EXT, l0);
    __syncthreads();
    // P1: merged g1|pv1 (S0 -> S2,S3), pwv12 (S1 -> S4)
    pw_mfma<128, 64, 64, true, false, false, false>(sh, SL{0,-1,-1}, SL{2,-1,-1}, SL{3,-1,-1},
        a.w[W_A1P], a.p[I_A1PB], a.p[I_V1B], 0, 88, l0);
    pw_mfma<64, 64, 64, false, false, false, false>(sh, SL{1,-1,-1}, SL{4,-1,-1}, SL{4,-1,-1},
        a.w[W_V12], a.p[I_V12B], a.p[I_V12B], 2, 86, l0);
    __syncthreads();
    // P2: xs2n issue (T14), a1 -> S5 + t1 = a1*pv1 in-place S3, xs2n -> S0
    {
        float xr[16];
        nl_issue(xr, xg, b, 128, 6, 82, l0);
        dw_mul<64, 7, 3, 16, false>(sh, SL{2,-1,-1}, SL{5,-1,-1}, SL{3,-1,-1}, a.p[I_A1DW], a.p[I_A1DB], 3, 85);
        nl_write(sh, 0, xr, 128, a.p[I_LN1W], a.p[I_LN1B], meanA, rstdA, 6, 82, l0);
    }
    __syncthreads();
    // P3: mul1 -> S2, x1low = dw3(S4)+S5 -> S1
    pw_mfma<64, 64, 64, false, false, false, false>(sh, SL{3,-1,-1}, SL{2,-1,-1}, SL{2,-1,-1},
        a.w[W_V11], a.p[I_V11B], a.p[I_V11B], 3, 85, l0);
    dw_ph<64, 3, 1, 11, true>(sh, SL{4,-1,-1}, SL{5,-1,-1}, SL{1,-1,-1}, a.p[I_C31W], a.p[I_C31B], 3, 85, l0);
    __syncthreads();
    // P4: ln2 STATS over raw {S1,S2}
    ln_stats<128>(sh, SL{1,2,-1}, 3, 85, scr, muRSB, rsB);
    __syncthreads();
    // P5: g2 LNF {S1,S2}->{S3,S4}; pv2 LNF INPL {S1,S2}
    pw_mfma<128, 128, 128, true, false, false, true>(sh, SL{1,2,-1}, SL{3,4,-1}, SL{3,4,-1},
        a.w[W_A2P], nullptr, nullptr, 3, 85, l0, a.uvA2, rsB, muRSB);
    pw_mfma<128, 128, 128, false, false, true, true>(sh, SL{1,2,-1}, SL{1,2,-1}, SL{1,2,-1},
        a.w[W_V2], nullptr, nullptr, 7, 81, l0, a.uvV2, rsB, muRSB);
    __syncthreads();
    // P6: pwv22 S0 -> S5, a2 = dw9 INPL {S3,S4} + t2 in-place {S1,S2}
    pw_mfma<64, 64, 64, false, false, false, false>(sh, SL{0,-1,-1}, SL{5,-1,-1}, SL{5,-1,-1},
        a.w[W_V22], a.p[I_V22B], a.p[I_V22B], 6, 82, l0);
    dw_mul<128, 9, 4, 19, true>(sh, SL{3,4,-1}, SL{3,4,-1}, SL{1,2,-1}, a.p[I_A2DW], a.p[I_A2DB], 7, 81);
    __syncthreads();
    // P7: p2a {S3,S4} -> S0, mul2 INPL {S1,S2}
    pw_mfma<64, 128, 64, false, false, false, false>(sh, SL{3,4,-1}, SL{0,-1,-1}, SL{0,-1,-1},
        a.w[W_P2], a.p[I_P2B], a.p[I_P2B], 7, 81, l0);
    pw_mfma<128, 128, 128, false, false, true, false>(sh, SL{1,2,-1}, SL{1,2,-1}, SL{1,2,-1},
        a.w[W_V21], a.p[I_V21B], a.p[I_V21B], 7, 81, l0);
    __syncthreads();
    // P8: x2low = dw3(S5)+S0 -> S3
    dw_ph<64, 3, 1, 10, true>(sh, SL{5,-1,-1}, SL{0,-1,-1}, SL{3,-1,-1}, a.p[I_C32W], a.p[I_C32B], 7, 81, l0);
    __syncthreads();
    // P9: ln3 STATS over raw {S3,S1,S2}
    ln_stats<192>(sh, SL{3,1,2}, 7, 81, scr, muRSB, rsB);
    __syncthreads();
    // P10: g3 LNF {S3,S1,S2}->{S4,S5,S0}; pv3 LNF INPL {S3,S1,S2}
    pw_mfma<192, 192, 192, true, false, false, true>(sh, SL{3,1,2}, SL{4,5,0}, SL{4,5,0},
        a.w[W_A3P], nullptr, nullptr, 7, 81, l0, a.uvA3, rsB, muRSB);
    pw_mfma<192, 192, 192, false, false, true, true>(sh, SL{3,1,2}, SL{3,1,2}, SL{3,1,2},
        a.w[W_V3], nullptr, nullptr, 12, 76, l0, a.uvV3, rsB, muRSB);
    __syncthreads();
    // P11: a3 = dw11 INPL {S4,S5,S0} + t3 in-place {S3,S1,S2}
    dw_mul<192, 11, 5, 32, true>(sh, SL{4,5,0}, SL{4,5,0}, SL{3,1,2}, a.p[I_A3DW], a.p[I_A3DB], 12, 76);
    __syncthreads();
    // P12: xs3n issue (T14); mul3 -> out[64:256]; p3a INPL {S4,S5,S0} -> S4;
    //      xs3n -> S5 (after p3a's internal barrier = all S5 reads done)
    {
        float xr[16];
        nl_issue(xr, xg, b, 192, 11, 77, l0);
        pw_mfma<192, 192, 192, false, true, false, false>(sh, SL{3,1,2}, SL{-1,-1,-1}, SL{-1,-1,-1},
            a.w[W_V31], a.p[I_V31B], a.p[I_V31B], 12, 76, l0,
            nullptr, nullptr, nullptr, a.out, b, 64);
        pw_mfma<64, 192, 64, false, false, true, false>(sh, SL{4,5,0}, SL{4,-1,-1}, SL{4,-1,-1},
            a.w[W_P3], a.p[I_P3B], a.p[I_P3B], 12, 76, l0);
        nl_write(sh, 5, xr, 192, a.p[I_LN1W], a.p[I_LN1B], meanA, rstdA, 11, 77, l0);
    }
    __syncthreads();
    // P13: pwv32 S5 -> S0
    pw_mfma<64, 64, 64, false, false, false, false>(sh, SL{5,-1,-1}, SL{0,-1,-1}, SL{0,-1,-1},
        a.w[W_V32], a.p[I_V32B], a.p[I_V32B], 11, 77, l0);
    __syncthreads();
    // P14: x3 = dw3(S0)+S4 -> out[0:64]
    dw3_glob(sh, 0, 4, a.p[I_C33W], a.p[I_C33B], a.out, b, l0);
}

extern "C" void kernel_launch(void* const* d_in, const int* in_sizes, int n_in,
                              void* d_out, int out_size, void* d_ws, size_t ws_size,
                              hipStream_t stream) {
    (void)in_sizes; (void)n_in; (void)out_size; (void)ws_size;
    static const int widx[W_N] = { I_A1PW, I_V1W, I_V11W, I_V12W, I_A2PW, I_V2W,
                                   I_V21W, I_V22W, I_P2W, I_A3PW, I_V3W, I_V31W,
                                   I_V32W, I_P3W };
    static const int wsz[W_N]  = { 4096, 4096, 4096, 4096, 16384, 16384, 16384,
                                   4096, 8192, 36864, 36864, 36864, 4096, 12288 };
    static const int wcd[W_N]  = { 64, 64, 64, 64, 128, 128, 128, 64, 128,
                                   192, 192, 192, 64, 192 };
    CvtArgs ca; KArgs ka;
    int off = 0;
    for (int i = 0; i < W_N; ++i) {
        ca.src[i]  = (const float*)d_in[widx[i]];
        ca.scl[i]  = nullptr;
        ca.cdim[i] = wcd[i];
        ca.off[i]  = off;
        off += wsz[i];
    }
    // fold LN2/LN3 scale into the LNF-consumed weight blobs
    ca.scl[W_A2P] = (const float*)d_in[I_LN2W];
    ca.scl[W_V2]  = (const float*)d_in[I_LN2W];
    ca.scl[W_A3P] = (const float*)d_in[I_LN3W];
    ca.scl[W_V3]  = (const float*)d_in[I_LN3W];
    ca.off[W_N] = off;                       // 204800 elems = 409600 B in d_ws
    ca.dst = (u16*)d_ws;
    for (int i = 0; i < 47; ++i) ka.p[i] = (const float*)d_in[i];
    for (int i = 0; i < W_N; ++i) ka.w[i] = (const u16*)d_ws + ca.off[i];
    // workspace: weights | LN1 stats (1 MiB) | uvA2(256f) uvV2(256f) uvA3(384f) uvV3(384f)
    const size_t stats_off = ((size_t)off * sizeof(u16) + 255) & ~(size_t)255;
    float* stats = (float*)((char*)d_ws + stats_off);
    float* uvA2  = stats + (size_t)32 * 4096 * 2;
    float* uvV2  = uvA2 + 256;
    float* uvA3  = uvV2 + 256;
    float* uvV3  = uvA3 + 384;
    ka.stats = stats;
    ka.uvA2 = uvA2; ka.uvV2 = uvV2; ka.uvA3 = uvA3; ka.uvV3 = uvV3;
    ka.out = (float*)d_out;

    UVArgs ua;
    ua.w2a = (const float*)d_in[I_A2PW]; ua.w2b = (const float*)d_in[I_V2W];
    ua.b2a = (const float*)d_in[I_A2PB]; ua.b2b = (const float*)d_in[I_V2B];
    ua.ln2b = (const float*)d_in[I_LN2B];
    ua.w3a = (const float*)d_in[I_A3PW]; ua.w3b = (const float*)d_in[I_V3W];
    ua.b3a = (const float*)d_in[I_A3PB]; ua.b3b = (const float*)d_in[I_V3B];
    ua.ln3b = (const float*)d_in[I_LN3B];
    ua.f2a = (const u16*)d_ws + ca.off[W_A2P];
    ua.f2b = (const u16*)d_ws + ca.off[W_V2];
    ua.f3a = (const u16*)d_ws + ca.off[W_A3P];
    ua.f3b = (const u16*)d_ws + ca.off[W_V3];
    ua.uvA2 = uvA2; ua.uvV2 = uvV2; ua.uvA3 = uvA3; ua.uvV3 = uvV3;

    cvt_kernel<<<dim3((off + 255) / 256), dim3(256), 0, stream>>>(ca);
    uv_kernel<<<dim3(640), dim3(64), 0, stream>>>(ua);
    ln1pre_kernel<<<dim3(32 * 64), dim3(256), 0, stream>>>((const float*)d_in[I_X], stats);
    convmod_kernel<<<dim3(32 * 64), dim3(NTHR), 0, stream>>>(ka);
}